// Round 5
// baseline (993.009 us; speedup 1.0000x reference)
//
#include <hip/hip_runtime.h>
#include <hip/hip_bf16.h>
#include <math.h>

#define N_NODES 100000
#define N_EDGES 1600000
#define NFEAT 512
#define NHID 128
#define NCLASS 40

#define SCAN_TILE 1024
#define SCAN_NB ((N_NODES + SCAN_TILE - 1) / SCAN_TILE)   // 98

// Bucketed edge sort: 128 nodes per bucket
#define BSH 7
#define BNODES (1 << BSH)                                  // 128
#define NBUCK ((N_NODES + BNODES - 1) / BNODES)            // 782

typedef short bf16x8 __attribute__((ext_vector_type(8)));
typedef float f32x4 __attribute__((ext_vector_type(4)));

static __device__ __forceinline__ unsigned short f32_to_bf16(float f) {
    unsigned int u = __float_as_uint(f);
    unsigned int r = u + 0x7FFFu + ((u >> 16) & 1u);   // RNE
    return (unsigned short)(r >> 16);
}
static __device__ __forceinline__ float bf16_to_f32(unsigned short h) {
    return __uint_as_float(((unsigned int)h) << 16);
}

// ---------------------------------------------------------------------------
// W1 transpose+convert (once per launch): W1[512][128] fp32 -> Wt[128][512] bf16
// ---------------------------------------------------------------------------
__global__ __launch_bounds__(256) void transpose_w1_kernel(
    const float* __restrict__ W1, unsigned short* __restrict__ Wt)
{
    int tid = blockIdx.x * 256 + threadIdx.x;    // 65536 total
    int n = tid >> 9;          // /512
    int k = tid & 511;
    Wt[tid] = f32_to_bf16(W1[k * NHID + n]);
}

// ---------------------------------------------------------------------------
// GEMM1 (bf16 MFMA): h1b[M,128](bf16) = features[M,512](fp32) @ W1
// ---------------------------------------------------------------------------
__global__ __launch_bounds__(256) void gemm1_mfma_kernel(
    const float* __restrict__ A,            // [M,512]
    const unsigned short* __restrict__ Wt,  // [128][512] bf16, Wt[n][k]
    unsigned short* __restrict__ h1b,       // [M,128] bf16
    int M)
{
    __shared__ unsigned short cstage[4][32 * 130];   // per-wave 32x128 (+2 pad)

    const int tid = threadIdx.x;
    const int w = tid >> 6;
    const int lane = tid & 63;
    const int lr = lane & 15;
    const int quad = lane >> 4;
    const int m0 = blockIdx.x * 128 + w * 32;   // this wave's 32 rows

    f32x4 acc[2][8];
    #pragma unroll
    for (int rt = 0; rt < 2; rt++)
        #pragma unroll
        for (int ct = 0; ct < 8; ct++)
            acc[rt][ct] = (f32x4){0.f, 0.f, 0.f, 0.f};

    int r0 = m0 + lr;
    int r1 = m0 + 16 + lr;
    int r0c = r0 < M ? r0 : M - 1;
    int r1c = r1 < M ? r1 : M - 1;
    const float* a0p = A + (size_t)r0c * NFEAT + quad * 8;
    const float* a1p = A + (size_t)r1c * NFEAT + quad * 8;
    const unsigned short* bp = Wt + (size_t)lr * NFEAT + quad * 8;

    #pragma unroll 2
    for (int k0 = 0; k0 < NFEAT; k0 += 32) {
        float4 a0a = *(const float4*)(a0p + k0);
        float4 a0b = *(const float4*)(a0p + k0 + 4);
        float4 a1a = *(const float4*)(a1p + k0);
        float4 a1b = *(const float4*)(a1p + k0 + 4);

        bf16x8 fb[8];
        #pragma unroll
        for (int ct = 0; ct < 8; ct++)
            fb[ct] = *(const bf16x8*)(bp + (size_t)ct * 16 * NFEAT + k0);

        bf16x8 fa0, fa1;
        fa0[0] = (short)f32_to_bf16(a0a.x); fa0[1] = (short)f32_to_bf16(a0a.y);
        fa0[2] = (short)f32_to_bf16(a0a.z); fa0[3] = (short)f32_to_bf16(a0a.w);
        fa0[4] = (short)f32_to_bf16(a0b.x); fa0[5] = (short)f32_to_bf16(a0b.y);
        fa0[6] = (short)f32_to_bf16(a0b.z); fa0[7] = (short)f32_to_bf16(a0b.w);
        fa1[0] = (short)f32_to_bf16(a1a.x); fa1[1] = (short)f32_to_bf16(a1a.y);
        fa1[2] = (short)f32_to_bf16(a1a.z); fa1[3] = (short)f32_to_bf16(a1a.w);
        fa1[4] = (short)f32_to_bf16(a1b.x); fa1[5] = (short)f32_to_bf16(a1b.y);
        fa1[6] = (short)f32_to_bf16(a1b.z); fa1[7] = (short)f32_to_bf16(a1b.w);

        #pragma unroll
        for (int ct = 0; ct < 8; ct++) {
            acc[0][ct] = __builtin_amdgcn_mfma_f32_16x16x32_bf16(fa0, fb[ct], acc[0][ct], 0, 0, 0);
            acc[1][ct] = __builtin_amdgcn_mfma_f32_16x16x32_bf16(fa1, fb[ct], acc[1][ct], 0, 0, 0);
        }
    }

    // Stage C to LDS (own wave region; no barrier needed), then coalesced store.
    unsigned short* st = cstage[w];
    #pragma unroll
    for (int rt = 0; rt < 2; rt++)
        #pragma unroll
        for (int ct = 0; ct < 8; ct++)
            #pragma unroll
            for (int i = 0; i < 4; i++) {
                int row = rt * 16 + quad * 4 + i;
                int col = ct * 16 + lr;
                st[row * 130 + col] = f32_to_bf16(acc[rt][ct][i]);
            }

    #pragma unroll
    for (int g = 0; g < 8; g++) {
        int row = g * 4 + (lane >> 4);          // 0..31
        int c8 = lane & 15;                      // 16B chunk index
        const unsigned short* rp = &st[row * 130 + c8 * 8];
        uint4 v = *(const uint4*)rp;
        int gr = m0 + row;
        if (gr < M)
            *(uint4*)&h1b[(size_t)gr * NHID + c8 * 8] = v;
    }
}

// ---------------------------------------------------------------------------
// Edge sort by dst: histogram -> hierarchical scan -> 2-pass bucketed scatter
// ---------------------------------------------------------------------------
__global__ __launch_bounds__(256) void hist_kernel(
    const int* __restrict__ dst, int* __restrict__ counts, int E)
{
    int e = blockIdx.x * 256 + threadIdx.x;
    if (e < E) atomicAdd(&counts[dst[e]], 1);
}

__global__ __launch_bounds__(256) void scan_partials_kernel(
    const int* __restrict__ counts, int* __restrict__ partials, int N)
{
    __shared__ int sh[256];
    const int t = threadIdx.x;
    const int base = blockIdx.x * SCAN_TILE + t * 4;
    int s = 0;
    #pragma unroll
    for (int j = 0; j < 4; j++) {
        int i = base + j;
        if (i < N) s += counts[i];
    }
    sh[t] = s;
    __syncthreads();
    #pragma unroll
    for (int off = 128; off > 0; off >>= 1) {
        if (t < off) sh[t] += sh[t + off];
        __syncthreads();
    }
    if (t == 0) partials[blockIdx.x] = sh[0];
}

__global__ __launch_bounds__(128) void scan_offsets_kernel(
    const int* __restrict__ partials, int* __restrict__ bofs,
    int* __restrict__ offsets, int N)
{
    __shared__ int sh[128];
    const int t = threadIdx.x;
    int v = (t < SCAN_NB) ? partials[t] : 0;
    sh[t] = v;
    __syncthreads();
    #pragma unroll
    for (int off = 1; off < 128; off <<= 1) {
        int u = (t >= off) ? sh[t - off] : 0;
        __syncthreads();
        sh[t] += u;
        __syncthreads();
    }
    if (t < SCAN_NB) bofs[t] = sh[t] - v;
    if (t == 127) offsets[N] = sh[127];
}

__global__ __launch_bounds__(256) void scan_final_kernel(
    const int* __restrict__ counts, const int* __restrict__ bofs,
    int* __restrict__ offsets, int N)
{
    __shared__ int sh[256];
    const int t = threadIdx.x;
    const int base = blockIdx.x * SCAN_TILE + t * 4;
    int c[4] = {0, 0, 0, 0};
    #pragma unroll
    for (int j = 0; j < 4; j++) {
        int i = base + j;
        if (i < N) c[j] = counts[i];
    }
    int s = c[0] + c[1] + c[2] + c[3];
    sh[t] = s;
    __syncthreads();
    #pragma unroll
    for (int off = 1; off < 256; off <<= 1) {
        int u = (t >= off) ? sh[t - off] : 0;
        __syncthreads();
        sh[t] += u;
        __syncthreads();
    }
    int run = bofs[blockIdx.x] + sh[t] - s;
    #pragma unroll
    for (int j = 0; j < 4; j++) {
        int i = base + j;
        if (i < N) {
            offsets[i] = run;
            run += c[j];
        }
    }
}

// bucket cursors = offsets at bucket-start nodes
__global__ __launch_bounds__(256) void bucket_init_kernel(
    const int* __restrict__ offsets, int* __restrict__ bcursor, int N)
{
    int b = blockIdx.x * 256 + threadIdx.x;
    if (b < NBUCK) {
        int nb = b << BSH;
        bcursor[b] = offsets[nb < N ? nb : N];
    }
}

// Pass A: append edges to their bucket region (sequential-ish full-line stores).
// Pack: x = src | (dst&127)<<17  (src < 2^17), y = weight bits.
__global__ __launch_bounds__(256) void bucket_scatter_kernel(
    const int* __restrict__ src, const int* __restrict__ dst,
    const float* __restrict__ w, int* __restrict__ bcursor,
    int2* __restrict__ sortedA, int E)
{
    int e = blockIdx.x * 256 + threadIdx.x;
    if (e >= E) return;
    int d = dst[e];
    int b = d >> BSH;
    int p = atomicAdd(&bcursor[b], 1);
    sortedA[p] = make_int2(src[e] | ((d & (BNODES - 1)) << 17), __float_as_int(w[e]));
}

// Pass B: one block per bucket; LDS node cursors; re-scatter within the
// bucket's ~16KB window into exact per-node order.
__global__ __launch_bounds__(256) void bucket_sort_kernel(
    const int2* __restrict__ sortedA, const int* __restrict__ offsets,
    int2* __restrict__ sortedB, int N)
{
    __shared__ int lcur[BNODES];
    const int b = blockIdx.x;
    const int t = threadIdx.x;
    const int nb = b << BSH;
    const int nn = min(BNODES, N - nb);
    if (t < nn) lcur[t] = offsets[nb + t];
    __syncthreads();
    const int beg = offsets[nb];
    const int end = offsets[nb + nn < N ? nb + nn : N];
    for (int e = beg + t; e < end; e += 256) {
        int2 v = sortedA[e];
        int dlow = (v.x >> 17) & (BNODES - 1);
        int s = v.x & 0x1FFFF;
        int p = atomicAdd(&lcur[dlow], 1);
        sortedB[p] = make_int2(s, v.y);
    }
}

// ---------------------------------------------------------------------------
// seg_agg1 (bf16 gather): x[n] = relu(sum w_e * h1b[src_e] + b1). 32 lanes/node.
// ---------------------------------------------------------------------------
__global__ __launch_bounds__(256) void seg_agg1_kernel(
    const int2* __restrict__ sorted, const int* __restrict__ offsets,
    const unsigned short* __restrict__ h1b, const float* __restrict__ b1,
    float* __restrict__ x, int N)
{
    const int tid = threadIdx.x;
    const int lane = tid & 31;
    const int node = blockIdx.x * 8 + (tid >> 5);
    if (node >= N) return;
    const int beg = offsets[node];
    const int end = offsets[node + 1];
    float4 acc = {0.f, 0.f, 0.f, 0.f};
    for (int c = beg; c < end; c += 32) {
        int m = end - c;
        if (m > 32) m = 32;
        int s = 0, wb = 0;
        if (lane < m) { int2 sw = sorted[c + lane]; s = sw.x; wb = sw.y; }
        for (int j = 0; j < m; j++) {
            int sj = __shfl(s, j, 32);
            float wj = __int_as_float(__shfl(wb, j, 32));
            ushort4 hv = *(const ushort4*)(h1b + (size_t)sj * NHID + lane * 4);
            acc.x = fmaf(wj, bf16_to_f32(hv.x), acc.x);
            acc.y = fmaf(wj, bf16_to_f32(hv.y), acc.y);
            acc.z = fmaf(wj, bf16_to_f32(hv.z), acc.z);
            acc.w = fmaf(wj, bf16_to_f32(hv.w), acc.w);
        }
    }
    float4 bb = *(const float4*)&b1[lane * 4];
    acc.x = fmaxf(acc.x + bb.x, 0.f);
    acc.y = fmaxf(acc.y + bb.y, 0.f);
    acc.z = fmaxf(acc.z + bb.z, 0.f);
    acc.w = fmaxf(acc.w + bb.w, 0.f);
    *(float4*)&x[(size_t)node * NHID + lane * 4] = acc;
}

// ---------------------------------------------------------------------------
// GEMM2 (fp32 vector): h2[M,40] = x[M,128] @ W2[128,40]
// ---------------------------------------------------------------------------
__global__ __launch_bounds__(256) void gemm2_kernel(
    const float* __restrict__ x, const float* __restrict__ W2,
    float* __restrict__ h2, int M)
{
    __shared__ float xs[32][128];
    __shared__ float Wt[40][132];

    const int tid = threadIdx.x;
    const int m0 = blockIdx.x * 32;

    #pragma unroll
    for (int i = 0; i < 4; i++) {
        int v = tid + i * 256;
        int row = v >> 5;
        int c4 = (v & 31) * 4;
        *(float4*)&xs[row][c4] = *(const float4*)&x[(size_t)(m0 + row) * NHID + c4];
    }
    #pragma unroll
    for (int i = 0; i < 20; i++) {
        int v = tid + i * 256;
        int k = v / 40;
        int c = v - k * 40;
        Wt[c][k] = W2[v];
    }
    __syncthreads();

    #pragma unroll
    for (int i = 0; i < 5; i++) {
        int o = tid + i * 256;
        int row = o / 40;
        int col = o - row * 40;
        float s = 0.f;
        #pragma unroll
        for (int k4 = 0; k4 < 32; k4++) {
            float4 x4 = *(float4*)&xs[row][k4 * 4];
            float4 w4 = *(float4*)&Wt[col][k4 * 4];
            s = fmaf(x4.x, w4.x, s);
            s = fmaf(x4.y, w4.y, s);
            s = fmaf(x4.z, w4.z, s);
            s = fmaf(x4.w, w4.w, s);
        }
        h2[(size_t)(m0 + row) * NCLASS + col] = s;
    }
}

// ---------------------------------------------------------------------------
// seg_agg2 + finalize: out[n] = log_softmax(sum w_e*h2[src_e] + b2).
// ---------------------------------------------------------------------------
__global__ __launch_bounds__(256) void seg_agg2_kernel(
    const int2* __restrict__ sorted, const int* __restrict__ offsets,
    const float* __restrict__ h2, const float* __restrict__ b2,
    float* __restrict__ out, int N)
{
    const int tid = threadIdx.x;
    const int lane = tid & 15;
    const int node = blockIdx.x * 16 + (tid >> 4);
    if (node >= N) return;
    const int beg = offsets[node];
    const int end = offsets[node + 1];
    float4 acc = {0.f, 0.f, 0.f, 0.f};
    for (int c = beg; c < end; c += 16) {
        int m = end - c;
        if (m > 16) m = 16;
        int s = 0, wb = 0;
        if (lane < m) { int2 sw = sorted[c + lane]; s = sw.x; wb = sw.y; }
        for (int j = 0; j < m; j++) {
            int sj = __shfl(s, j, 16);
            float wj = __int_as_float(__shfl(wb, j, 16));
            if (lane < 10) {
                float4 v = *(const float4*)&h2[(size_t)sj * NCLASS + lane * 4];
                acc.x = fmaf(wj, v.x, acc.x);
                acc.y = fmaf(wj, v.y, acc.y);
                acc.z = fmaf(wj, v.z, acc.z);
                acc.w = fmaf(wj, v.w, acc.w);
            }
        }
    }
    float mx;
    if (lane < 10) {
        float4 bb = *(const float4*)&b2[lane * 4];
        acc.x += bb.x; acc.y += bb.y; acc.z += bb.z; acc.w += bb.w;
        mx = fmaxf(fmaxf(acc.x, acc.y), fmaxf(acc.z, acc.w));
    } else {
        mx = -INFINITY;
    }
    #pragma unroll
    for (int o = 8; o > 0; o >>= 1) mx = fmaxf(mx, __shfl_xor(mx, o, 16));
    float sm = 0.f;
    if (lane < 10)
        sm = expf(acc.x - mx) + expf(acc.y - mx) + expf(acc.z - mx) + expf(acc.w - mx);
    #pragma unroll
    for (int o = 8; o > 0; o >>= 1) sm += __shfl_xor(sm, o, 16);
    if (lane < 10) {
        float l = mx + logf(sm);
        float4 o4 = {acc.x - l, acc.y - l, acc.z - l, acc.w - l};
        *(float4*)&out[(size_t)node * NCLASS + lane * 4] = o4;
    }
}

extern "C" void kernel_launch(void* const* d_in, const int* in_sizes, int n_in,
                              void* d_out, int out_size, void* d_ws, size_t ws_size,
                              hipStream_t stream) {
    const float* features = (const float*)d_in[0];
    const int* edge_src   = (const int*)d_in[1];
    const int* edge_dst   = (const int*)d_in[2];
    const float* edge_w   = (const float*)d_in[3];
    const float* W1       = (const float*)d_in[4];
    const float* b1       = (const float*)d_in[5];
    const float* W2       = (const float*)d_in[6];
    const float* b2       = (const float*)d_in[7];
    float* out = (float*)d_out;

    // Workspace layout (bytes from base):
    //   x:        fp32 [N,128]            @ 0          (51,200,000)
    //   h1b:      bf16 [N,128]            @ 51,200,000 (25,600,000; reused as h2)
    //   Wt:       bf16 [128,512]          @ 76,800,000 (131,072)
    //   sortedB:  int2 [E]                @ 76,931,072 (12,800,000)
    //   offsets:  int  [N+1]              @ 89,731,072 (400,008)
    //   counts:   int  [N]                @ 90,131,080 (400,000)
    //   partials: int  [98]               @ 90,531,080
    //   bofs:     int  [98]               @ 90,531,472
    //   bcursor:  int  [NBUCK=782]        @ 90,532,000
    //   sortedA:  int2 [E]                @ 90,540,000 (12,800,000)
    char* base = (char*)d_ws;
    float*          x        = (float*)base;
    unsigned short* h1b      = (unsigned short*)(base + 51200000);
    unsigned short* Wt       = (unsigned short*)(base + 76800000);
    int2*           sortedB  = (int2*)(base + 76931072);
    int*            offsets  = (int*)(base + 89731072);
    int*            counts   = (int*)(base + 90131080);
    int*            partials = (int*)(base + 90531080);
    int*            bofs     = (int*)(base + 90531472);
    int*            bcursor  = (int*)(base + 90532000);
    int2*           sortedA  = (int2*)(base + 90540000);
    float*          h2       = (float*)h1b;   // h1b dead after seg_agg1

    hipMemsetAsync(counts, 0, N_NODES * sizeof(int), stream);

    // Edge sort by dst (bucketed two-pass)
    hist_kernel<<<(N_EDGES + 255) / 256, 256, 0, stream>>>(edge_dst, counts, N_EDGES);
    scan_partials_kernel<<<SCAN_NB, 256, 0, stream>>>(counts, partials, N_NODES);
    scan_offsets_kernel<<<1, 128, 0, stream>>>(partials, bofs, offsets, N_NODES);
    scan_final_kernel<<<SCAN_NB, 256, 0, stream>>>(counts, bofs, offsets, N_NODES);
    bucket_init_kernel<<<(NBUCK + 255) / 256, 256, 0, stream>>>(offsets, bcursor, N_NODES);
    bucket_scatter_kernel<<<(N_EDGES + 255) / 256, 256, 0, stream>>>(
        edge_src, edge_dst, edge_w, bcursor, sortedA, N_EDGES);
    bucket_sort_kernel<<<NBUCK, 256, 0, stream>>>(sortedA, offsets, sortedB, N_NODES);

    // Dense layer 1: bf16 MFMA
    transpose_w1_kernel<<<(NFEAT * NHID) / 256, 256, 0, stream>>>(W1, Wt);
    gemm1_mfma_kernel<<<(N_NODES + 127) / 128, 256, 0, stream>>>(features, Wt, h1b, N_NODES);

    // Aggregate 1 (+bias+relu fused)
    seg_agg1_kernel<<<(N_NODES + 7) / 8, 256, 0, stream>>>(
        sortedB, offsets, h1b, b1, x, N_NODES);

    // Dense layer 2 (fp32)
    gemm2_kernel<<<(N_NODES + 31) / 32, 256, 0, stream>>>(x, W2, h2, N_NODES);

    // Aggregate 2 + bias + log_softmax fused
    seg_agg2_kernel<<<(N_NODES + 15) / 16, 256, 0, stream>>>(
        sortedB, offsets, h2, b2, out, N_NODES);
}

// Round 6
// 646.195 us; speedup vs baseline: 1.5367x; 1.5367x over previous
//
#include <hip/hip_runtime.h>
#include <hip/hip_bf16.h>
#include <math.h>

#define N_NODES 100000
#define N_EDGES 1600000
#define NFEAT 512
#define NHID 128
#define NCLASS 40

#define SCAN_TILE 1024
#define SCAN_NB ((N_NODES + SCAN_TILE - 1) / SCAN_TILE)   // 98

// Bucketed edge sort: 256 nodes per bucket
#define BSH 8
#define BNODES (1 << BSH)                                  // 256
#define NBUCK ((N_NODES + BNODES - 1) / BNODES)            // 391

// Partition kernel: edges per block / per thread
#define PCHUNK 4096
#define PEPT 16
#define PNB ((N_EDGES + PCHUNK - 1) / PCHUNK)              // 391

typedef short bf16x8 __attribute__((ext_vector_type(8)));
typedef float f32x4 __attribute__((ext_vector_type(4)));

static __device__ __forceinline__ unsigned short f32_to_bf16(float f) {
    unsigned int u = __float_as_uint(f);
    unsigned int r = u + 0x7FFFu + ((u >> 16) & 1u);   // RNE
    return (unsigned short)(r >> 16);
}
static __device__ __forceinline__ float bf16_to_f32(unsigned short h) {
    return __uint_as_float(((unsigned int)h) << 16);
}

// ---------------------------------------------------------------------------
// W1 transpose+convert (once per launch): W1[512][128] fp32 -> Wt[128][512] bf16
// ---------------------------------------------------------------------------
__global__ __launch_bounds__(256) void transpose_w1_kernel(
    const float* __restrict__ W1, unsigned short* __restrict__ Wt)
{
    int tid = blockIdx.x * 256 + threadIdx.x;    // 65536 total
    int n = tid >> 9;          // /512
    int k = tid & 511;
    Wt[tid] = f32_to_bf16(W1[k * NHID + n]);
}

// ---------------------------------------------------------------------------
// GEMM1 (bf16 MFMA): h1b[M,128](bf16) = features[M,512](fp32) @ W1
// ---------------------------------------------------------------------------
__global__ __launch_bounds__(256) void gemm1_mfma_kernel(
    const float* __restrict__ A,            // [M,512]
    const unsigned short* __restrict__ Wt,  // [128][512] bf16, Wt[n][k]
    unsigned short* __restrict__ h1b,       // [M,128] bf16
    int M)
{
    __shared__ unsigned short cstage[4][32 * 130];   // per-wave 32x128 (+2 pad)

    const int tid = threadIdx.x;
    const int w = tid >> 6;
    const int lane = tid & 63;
    const int lr = lane & 15;
    const int quad = lane >> 4;
    const int m0 = blockIdx.x * 128 + w * 32;   // this wave's 32 rows

    f32x4 acc[2][8];
    #pragma unroll
    for (int rt = 0; rt < 2; rt++)
        #pragma unroll
        for (int ct = 0; ct < 8; ct++)
            acc[rt][ct] = (f32x4){0.f, 0.f, 0.f, 0.f};

    int r0 = m0 + lr;
    int r1 = m0 + 16 + lr;
    int r0c = r0 < M ? r0 : M - 1;
    int r1c = r1 < M ? r1 : M - 1;
    const float* a0p = A + (size_t)r0c * NFEAT + quad * 8;
    const float* a1p = A + (size_t)r1c * NFEAT + quad * 8;
    const unsigned short* bp = Wt + (size_t)lr * NFEAT + quad * 8;

    #pragma unroll 2
    for (int k0 = 0; k0 < NFEAT; k0 += 32) {
        float4 a0a = *(const float4*)(a0p + k0);
        float4 a0b = *(const float4*)(a0p + k0 + 4);
        float4 a1a = *(const float4*)(a1p + k0);
        float4 a1b = *(const float4*)(a1p + k0 + 4);

        bf16x8 fb[8];
        #pragma unroll
        for (int ct = 0; ct < 8; ct++)
            fb[ct] = *(const bf16x8*)(bp + (size_t)ct * 16 * NFEAT + k0);

        bf16x8 fa0, fa1;
        fa0[0] = (short)f32_to_bf16(a0a.x); fa0[1] = (short)f32_to_bf16(a0a.y);
        fa0[2] = (short)f32_to_bf16(a0a.z); fa0[3] = (short)f32_to_bf16(a0a.w);
        fa0[4] = (short)f32_to_bf16(a0b.x); fa0[5] = (short)f32_to_bf16(a0b.y);
        fa0[6] = (short)f32_to_bf16(a0b.z); fa0[7] = (short)f32_to_bf16(a0b.w);
        fa1[0] = (short)f32_to_bf16(a1a.x); fa1[1] = (short)f32_to_bf16(a1a.y);
        fa1[2] = (short)f32_to_bf16(a1a.z); fa1[3] = (short)f32_to_bf16(a1a.w);
        fa1[4] = (short)f32_to_bf16(a1b.x); fa1[5] = (short)f32_to_bf16(a1b.y);
        fa1[6] = (short)f32_to_bf16(a1b.z); fa1[7] = (short)f32_to_bf16(a1b.w);

        #pragma unroll
        for (int ct = 0; ct < 8; ct++) {
            acc[0][ct] = __builtin_amdgcn_mfma_f32_16x16x32_bf16(fa0, fb[ct], acc[0][ct], 0, 0, 0);
            acc[1][ct] = __builtin_amdgcn_mfma_f32_16x16x32_bf16(fa1, fb[ct], acc[1][ct], 0, 0, 0);
        }
    }

    // Stage C to LDS (own wave region; no barrier needed), then coalesced store.
    unsigned short* st = cstage[w];
    #pragma unroll
    for (int rt = 0; rt < 2; rt++)
        #pragma unroll
        for (int ct = 0; ct < 8; ct++)
            #pragma unroll
            for (int i = 0; i < 4; i++) {
                int row = rt * 16 + quad * 4 + i;
                int col = ct * 16 + lr;
                st[row * 130 + col] = f32_to_bf16(acc[rt][ct][i]);
            }

    #pragma unroll
    for (int g = 0; g < 8; g++) {
        int row = g * 4 + (lane >> 4);          // 0..31
        int c8 = lane & 15;                      // 16B chunk index
        const unsigned short* rp = &st[row * 130 + c8 * 8];
        uint4 v = *(const uint4*)rp;
        int gr = m0 + row;
        if (gr < M)
            *(uint4*)&h1b[(size_t)gr * NHID + c8 * 8] = v;
    }
}

// ---------------------------------------------------------------------------
// Edge sort by dst: histogram -> hierarchical scan -> LDS-staged partition
// into buckets -> within-bucket node sort.
// ---------------------------------------------------------------------------
__global__ __launch_bounds__(256) void hist_kernel(
    const int* __restrict__ dst, int* __restrict__ counts, int E)
{
    int e = blockIdx.x * 256 + threadIdx.x;
    if (e < E) atomicAdd(&counts[dst[e]], 1);
}

__global__ __launch_bounds__(256) void scan_partials_kernel(
    const int* __restrict__ counts, int* __restrict__ partials, int N)
{
    __shared__ int sh[256];
    const int t = threadIdx.x;
    const int base = blockIdx.x * SCAN_TILE + t * 4;
    int s = 0;
    #pragma unroll
    for (int j = 0; j < 4; j++) {
        int i = base + j;
        if (i < N) s += counts[i];
    }
    sh[t] = s;
    __syncthreads();
    #pragma unroll
    for (int off = 128; off > 0; off >>= 1) {
        if (t < off) sh[t] += sh[t + off];
        __syncthreads();
    }
    if (t == 0) partials[blockIdx.x] = sh[0];
}

__global__ __launch_bounds__(128) void scan_offsets_kernel(
    const int* __restrict__ partials, int* __restrict__ bofs,
    int* __restrict__ offsets, int N)
{
    __shared__ int sh[128];
    const int t = threadIdx.x;
    int v = (t < SCAN_NB) ? partials[t] : 0;
    sh[t] = v;
    __syncthreads();
    #pragma unroll
    for (int off = 1; off < 128; off <<= 1) {
        int u = (t >= off) ? sh[t - off] : 0;
        __syncthreads();
        sh[t] += u;
        __syncthreads();
    }
    if (t < SCAN_NB) bofs[t] = sh[t] - v;
    if (t == 127) offsets[N] = sh[127];
}

__global__ __launch_bounds__(256) void scan_final_kernel(
    const int* __restrict__ counts, const int* __restrict__ bofs,
    int* __restrict__ offsets, int N)
{
    __shared__ int sh[256];
    const int t = threadIdx.x;
    const int base = blockIdx.x * SCAN_TILE + t * 4;
    int c[4] = {0, 0, 0, 0};
    #pragma unroll
    for (int j = 0; j < 4; j++) {
        int i = base + j;
        if (i < N) c[j] = counts[i];
    }
    int s = c[0] + c[1] + c[2] + c[3];
    sh[t] = s;
    __syncthreads();
    #pragma unroll
    for (int off = 1; off < 256; off <<= 1) {
        int u = (t >= off) ? sh[t - off] : 0;
        __syncthreads();
        sh[t] += u;
        __syncthreads();
    }
    int run = bofs[blockIdx.x] + sh[t] - s;
    #pragma unroll
    for (int j = 0; j < 4; j++) {
        int i = base + j;
        if (i < N) {
            offsets[i] = run;
            run += c[j];
        }
    }
}

// bucket cursors = offsets at bucket-start nodes
__global__ __launch_bounds__(256) void bucket_init_kernel(
    const int* __restrict__ offsets, int* __restrict__ bcursor, int N)
{
    int b = blockIdx.x * 256 + threadIdx.x;
    if (b < NBUCK) {
        int nb = b << BSH;
        bcursor[b] = offsets[nb < N ? nb : N];
    }
}

// Pass A: LDS-staged partition. Each block: 4096 contiguous edges ->
// per-block LDS histogram -> ONE global atomic per (block,bucket) to reserve
// a run -> scatter via LDS cursors so each block's edges for a bucket land
// in consecutive slots (full-line writes, low atomic contention).
// Pack: x = src | (dst & 255) << 17  (src < 2^17), y = weight bits.
__global__ __launch_bounds__(256) void partition_kernel(
    const int* __restrict__ src, const int* __restrict__ dst,
    const float* __restrict__ w, int* __restrict__ bcursor,
    int2* __restrict__ sortedA, int E)
{
    __shared__ int hist[NBUCK];
    __shared__ int bbase[NBUCK];
    const int t = threadIdx.x;
    const int c0 = blockIdx.x * PCHUNK;

    for (int j = t; j < NBUCK; j += 256) hist[j] = 0;
    __syncthreads();

    int  myb[PEPT];
    int2 myv[PEPT];
    #pragma unroll
    for (int i = 0; i < PEPT; i++) {
        int e = c0 + t + i * 256;
        if (e < E) {
            int d = dst[e];
            myb[i] = d >> BSH;
            myv[i] = make_int2(src[e] | ((d & (BNODES - 1)) << 17),
                               __float_as_int(w[e]));
            atomicAdd(&hist[myb[i]], 1);
        } else {
            myb[i] = -1;
        }
    }
    __syncthreads();

    for (int j = t; j < NBUCK; j += 256) {
        int c = hist[j];
        bbase[j] = c ? atomicAdd(&bcursor[j], c) : 0;
    }
    __syncthreads();

    #pragma unroll
    for (int i = 0; i < PEPT; i++) {
        if (myb[i] >= 0) {
            int p = atomicAdd(&bbase[myb[i]], 1);
            sortedA[p] = myv[i];
        }
    }
}

// Pass B: one block per bucket; LDS node cursors; re-scatter within the
// bucket's ~32KB window into exact per-node order.
__global__ __launch_bounds__(256) void bucket_sort_kernel(
    const int2* __restrict__ sortedA, const int* __restrict__ offsets,
    int2* __restrict__ sortedB, int N)
{
    __shared__ int lcur[BNODES];
    const int b = blockIdx.x;
    const int t = threadIdx.x;
    const int nb = b << BSH;
    const int nn = min(BNODES, N - nb);
    if (t < nn) lcur[t] = offsets[nb + t];
    __syncthreads();
    const int beg = offsets[nb];
    const int end = offsets[nb + nn < N ? nb + nn : N];
    for (int e = beg + t; e < end; e += 256) {
        int2 v = sortedA[e];
        int dlow = (v.x >> 17) & (BNODES - 1);
        int s = v.x & 0x1FFFF;
        int p = atomicAdd(&lcur[dlow], 1);
        sortedB[p] = make_int2(s, v.y);
    }
}

// ---------------------------------------------------------------------------
// seg_agg1 (bf16 gather): x[n] = relu(sum w_e * h1b[src_e] + b1). 32 lanes/node.
// ---------------------------------------------------------------------------
__global__ __launch_bounds__(256) void seg_agg1_kernel(
    const int2* __restrict__ sorted, const int* __restrict__ offsets,
    const unsigned short* __restrict__ h1b, const float* __restrict__ b1,
    float* __restrict__ x, int N)
{
    const int tid = threadIdx.x;
    const int lane = tid & 31;
    const int node = blockIdx.x * 8 + (tid >> 5);
    if (node >= N) return;
    const int beg = offsets[node];
    const int end = offsets[node + 1];
    float4 acc = {0.f, 0.f, 0.f, 0.f};
    for (int c = beg; c < end; c += 32) {
        int m = end - c;
        if (m > 32) m = 32;
        int s = 0, wb = 0;
        if (lane < m) { int2 sw = sorted[c + lane]; s = sw.x; wb = sw.y; }
        for (int j = 0; j < m; j++) {
            int sj = __shfl(s, j, 32);
            float wj = __int_as_float(__shfl(wb, j, 32));
            ushort4 hv = *(const ushort4*)(h1b + (size_t)sj * NHID + lane * 4);
            acc.x = fmaf(wj, bf16_to_f32(hv.x), acc.x);
            acc.y = fmaf(wj, bf16_to_f32(hv.y), acc.y);
            acc.z = fmaf(wj, bf16_to_f32(hv.z), acc.z);
            acc.w = fmaf(wj, bf16_to_f32(hv.w), acc.w);
        }
    }
    float4 bb = *(const float4*)&b1[lane * 4];
    acc.x = fmaxf(acc.x + bb.x, 0.f);
    acc.y = fmaxf(acc.y + bb.y, 0.f);
    acc.z = fmaxf(acc.z + bb.z, 0.f);
    acc.w = fmaxf(acc.w + bb.w, 0.f);
    *(float4*)&x[(size_t)node * NHID + lane * 4] = acc;
}

// ---------------------------------------------------------------------------
// GEMM2 (fp32 vector): h2[M,40] = x[M,128] @ W2[128,40]
// ---------------------------------------------------------------------------
__global__ __launch_bounds__(256) void gemm2_kernel(
    const float* __restrict__ x, const float* __restrict__ W2,
    float* __restrict__ h2, int M)
{
    __shared__ float xs[32][128];
    __shared__ float Wt[40][132];

    const int tid = threadIdx.x;
    const int m0 = blockIdx.x * 32;

    #pragma unroll
    for (int i = 0; i < 4; i++) {
        int v = tid + i * 256;
        int row = v >> 5;
        int c4 = (v & 31) * 4;
        *(float4*)&xs[row][c4] = *(const float4*)&x[(size_t)(m0 + row) * NHID + c4];
    }
    #pragma unroll
    for (int i = 0; i < 20; i++) {
        int v = tid + i * 256;
        int k = v / 40;
        int c = v - k * 40;
        Wt[c][k] = W2[v];
    }
    __syncthreads();

    #pragma unroll
    for (int i = 0; i < 5; i++) {
        int o = tid + i * 256;
        int row = o / 40;
        int col = o - row * 40;
        float s = 0.f;
        #pragma unroll
        for (int k4 = 0; k4 < 32; k4++) {
            float4 x4 = *(float4*)&xs[row][k4 * 4];
            float4 w4 = *(float4*)&Wt[col][k4 * 4];
            s = fmaf(x4.x, w4.x, s);
            s = fmaf(x4.y, w4.y, s);
            s = fmaf(x4.z, w4.z, s);
            s = fmaf(x4.w, w4.w, s);
        }
        h2[(size_t)(m0 + row) * NCLASS + col] = s;
    }
}

// ---------------------------------------------------------------------------
// seg_agg2 + finalize: out[n] = log_softmax(sum w_e*h2[src_e] + b2).
// ---------------------------------------------------------------------------
__global__ __launch_bounds__(256) void seg_agg2_kernel(
    const int2* __restrict__ sorted, const int* __restrict__ offsets,
    const float* __restrict__ h2, const float* __restrict__ b2,
    float* __restrict__ out, int N)
{
    const int tid = threadIdx.x;
    const int lane = tid & 15;
    const int node = blockIdx.x * 16 + (tid >> 4);
    if (node >= N) return;
    const int beg = offsets[node];
    const int end = offsets[node + 1];
    float4 acc = {0.f, 0.f, 0.f, 0.f};
    for (int c = beg; c < end; c += 16) {
        int m = end - c;
        if (m > 16) m = 16;
        int s = 0, wb = 0;
        if (lane < m) { int2 sw = sorted[c + lane]; s = sw.x; wb = sw.y; }
        for (int j = 0; j < m; j++) {
            int sj = __shfl(s, j, 16);
            float wj = __int_as_float(__shfl(wb, j, 16));
            if (lane < 10) {
                float4 v = *(const float4*)&h2[(size_t)sj * NCLASS + lane * 4];
                acc.x = fmaf(wj, v.x, acc.x);
                acc.y = fmaf(wj, v.y, acc.y);
                acc.z = fmaf(wj, v.z, acc.z);
                acc.w = fmaf(wj, v.w, acc.w);
            }
        }
    }
    float mx;
    if (lane < 10) {
        float4 bb = *(const float4*)&b2[lane * 4];
        acc.x += bb.x; acc.y += bb.y; acc.z += bb.z; acc.w += bb.w;
        mx = fmaxf(fmaxf(acc.x, acc.y), fmaxf(acc.z, acc.w));
    } else {
        mx = -INFINITY;
    }
    #pragma unroll
    for (int o = 8; o > 0; o >>= 1) mx = fmaxf(mx, __shfl_xor(mx, o, 16));
    float sm = 0.f;
    if (lane < 10)
        sm = expf(acc.x - mx) + expf(acc.y - mx) + expf(acc.z - mx) + expf(acc.w - mx);
    #pragma unroll
    for (int o = 8; o > 0; o >>= 1) sm += __shfl_xor(sm, o, 16);
    if (lane < 10) {
        float l = mx + logf(sm);
        float4 o4 = {acc.x - l, acc.y - l, acc.z - l, acc.w - l};
        *(float4*)&out[(size_t)node * NCLASS + lane * 4] = o4;
    }
}

extern "C" void kernel_launch(void* const* d_in, const int* in_sizes, int n_in,
                              void* d_out, int out_size, void* d_ws, size_t ws_size,
                              hipStream_t stream) {
    const float* features = (const float*)d_in[0];
    const int* edge_src   = (const int*)d_in[1];
    const int* edge_dst   = (const int*)d_in[2];
    const float* edge_w   = (const float*)d_in[3];
    const float* W1       = (const float*)d_in[4];
    const float* b1       = (const float*)d_in[5];
    const float* W2       = (const float*)d_in[6];
    const float* b2       = (const float*)d_in[7];
    float* out = (float*)d_out;

    // Workspace layout (bytes from base):
    //   x:        fp32 [N,128]            @ 0          (51,200,000)
    //   h1b:      bf16 [N,128]            @ 51,200,000 (25,600,000; reused as h2)
    //   Wt:       bf16 [128,512]          @ 76,800,000 (131,072)
    //   sortedB:  int2 [E]                @ 76,931,072 (12,800,000)
    //   offsets:  int  [N+1]              @ 89,731,072 (400,008)
    //   counts:   int  [N]                @ 90,131,080 (400,000)
    //   partials: int  [98]               @ 90,531,080
    //   bofs:     int  [98]               @ 90,531,472
    //   bcursor:  int  [NBUCK=391]        @ 90,532,000
    //   sortedA:  int2 [E]                @ 90,540,000 (12,800,000)
    char* base = (char*)d_ws;
    float*          x        = (float*)base;
    unsigned short* h1b      = (unsigned short*)(base + 51200000);
    unsigned short* Wt       = (unsigned short*)(base + 76800000);
    int2*           sortedB  = (int2*)(base + 76931072);
    int*            offsets  = (int*)(base + 89731072);
    int*            counts   = (int*)(base + 90131080);
    int*            partials = (int*)(base + 90531080);
    int*            bofs     = (int*)(base + 90531472);
    int*            bcursor  = (int*)(base + 90532000);
    int2*           sortedA  = (int2*)(base + 90540000);
    float*          h2       = (float*)h1b;   // h1b dead after seg_agg1

    hipMemsetAsync(counts, 0, N_NODES * sizeof(int), stream);

    // Edge sort by dst (LDS-staged partition + within-bucket sort)
    hist_kernel<<<(N_EDGES + 255) / 256, 256, 0, stream>>>(edge_dst, counts, N_EDGES);
    scan_partials_kernel<<<SCAN_NB, 256, 0, stream>>>(counts, partials, N_NODES);
    scan_offsets_kernel<<<1, 128, 0, stream>>>(partials, bofs, offsets, N_NODES);
    scan_final_kernel<<<SCAN_NB, 256, 0, stream>>>(counts, bofs, offsets, N_NODES);
    bucket_init_kernel<<<(NBUCK + 255) / 256, 256, 0, stream>>>(offsets, bcursor, N_NODES);
    partition_kernel<<<PNB, 256, 0, stream>>>(
        edge_src, edge_dst, edge_w, bcursor, sortedA, N_EDGES);
    bucket_sort_kernel<<<NBUCK, 256, 0, stream>>>(sortedA, offsets, sortedB, N_NODES);

    // Dense layer 1: bf16 MFMA
    transpose_w1_kernel<<<(NFEAT * NHID) / 256, 256, 0, stream>>>(W1, Wt);
    gemm1_mfma_kernel<<<(N_NODES + 127) / 128, 256, 0, stream>>>(features, Wt, h1b, N_NODES);

    // Aggregate 1 (+bias+relu fused)
    seg_agg1_kernel<<<(N_NODES + 7) / 8, 256, 0, stream>>>(
        sortedB, offsets, h1b, b1, x, N_NODES);

    // Dense layer 2 (fp32)
    gemm2_kernel<<<(N_NODES + 31) / 32, 256, 0, stream>>>(x, W2, h2, N_NODES);

    // Aggregate 2 + bias + log_softmax fused
    seg_agg2_kernel<<<(N_NODES + 15) / 16, 256, 0, stream>>>(
        sortedB, offsets, h2, b2, out, N_NODES);
}